// Round 1
// baseline (372.943 us; speedup 1.0000x reference)
//
#include <hip/hip_runtime.h>
#include <hip/hip_bf16.h>
#include <math.h>

#define S_LEN 2048
#define BATCH 2
#define HID 1024
#define NHEAD 16
#define HDIM 64
#define NTOK (S_LEN*BATCH)   // 4096

typedef __bf16 bf16;
typedef __bf16 bf16x8 __attribute__((ext_vector_type(8)));
typedef float f32x4 __attribute__((ext_vector_type(4)));

typedef const __attribute__((address_space(1))) unsigned int* gptr_t;
typedef __attribute__((address_space(3))) unsigned int* lptr_t;

__device__ __forceinline__ void gload16(const void* g, void* l) {
    __builtin_amdgcn_global_load_lds((gptr_t)g, (lptr_t)l, 16, 0, 0);
}

// ---------------- fp32 -> bf16 convert (8 elems/thread) ----------------
__global__ void cvt_f32_bf16(const float* __restrict__ src, bf16* __restrict__ dst, int n) {
    int i = (blockIdx.x * blockDim.x + threadIdx.x) * 8;
    if (i >= n) return;
    const float4* s = (const float4*)(src + i);
    float4 a = s[0], b = s[1];
    bf16x8 o;
    o[0] = (bf16)a.x; o[1] = (bf16)a.y; o[2] = (bf16)a.z; o[3] = (bf16)a.w;
    o[4] = (bf16)b.x; o[5] = (bf16)b.y; o[6] = (bf16)b.z; o[7] = (bf16)b.w;
    *(bf16x8*)(dst + i) = o;
}

// ---------------- GEMM: C[M][N] = A[M][K] * B[N][K]^T  (both row-major, K contig) ----
// 128x128 tile, BK=32, 4 waves (each 64x64 = 4x4 MFMA tiles of 16x16x32 bf16).
// mode 0: QKV epilogue (N=3072): scatter to q/k/v head layout [32][2048][64] bf16
// mode 1: OUT epilogue (N=1024): fp32 token-major + bias
#define BM 128
#define BN 128
#define BK 32

__global__ __launch_bounds__(256) void gemm_bt(
    const bf16* __restrict__ A, const bf16* __restrict__ B,
    int M, int N, int K, int mode,
    const float* __restrict__ bq, const float* __restrict__ bk,
    const float* __restrict__ bv, const float* __restrict__ bo,
    bf16* __restrict__ qh, bf16* __restrict__ kh, bf16* __restrict__ vh,
    float* __restrict__ outp)
{
    __shared__ __align__(16) bf16 As[BM * BK];
    __shared__ __align__(16) bf16 Bs[BN * BK];
    const int tid = threadIdx.x;
    const int lane = tid & 63, wv = tid >> 6;
    const int g = lane >> 4, l15 = lane & 15;
    const int wr = wv >> 1, wc = wv & 1;
    const int bm = blockIdx.y * BM, bn = blockIdx.x * BN;

    f32x4 zero4 = {0.f, 0.f, 0.f, 0.f};
    f32x4 acc[4][4];
#pragma unroll
    for (int mi = 0; mi < 4; mi++)
#pragma unroll
        for (int ni = 0; ni < 4; ni++) acc[mi][ni] = zero4;

    // staging: wave wv stages rows [wv*32, wv*32+32) of A-tile and B-tile.
    const int r0 = wv * 32 + (lane >> 2);
    const int c0 = (lane & 3) * 8;
    const bf16* Ag0 = A + (size_t)(bm + r0) * K + c0;
    const bf16* Ag1 = Ag0 + (size_t)16 * K;
    const bf16* Bg0 = B + (size_t)(bn + r0) * K + c0;
    const bf16* Bg1 = Bg0 + (size_t)16 * K;
    bf16* AsW = &As[(wv * 32) * BK];   // wave-uniform LDS base
    bf16* BsW = &Bs[(wv * 32) * BK];

    for (int k0 = 0; k0 < K; k0 += BK) {
        gload16(Ag0 + k0, AsW);
        gload16(Ag1 + k0, AsW + 16 * BK);
        gload16(Bg0 + k0, BsW);
        gload16(Bg1 + k0, BsW + 16 * BK);
        __syncthreads();   // compiler drains vmcnt before barrier

        bf16x8 aF[4], bF[4];
#pragma unroll
        for (int mi = 0; mi < 4; mi++)
            aF[mi] = *(const bf16x8*)&As[(wr * 64 + mi * 16 + l15) * BK + g * 8];
#pragma unroll
        for (int ni = 0; ni < 4; ni++)
            bF[ni] = *(const bf16x8*)&Bs[(wc * 64 + ni * 16 + l15) * BK + g * 8];
#pragma unroll
        for (int mi = 0; mi < 4; mi++)
#pragma unroll
            for (int ni = 0; ni < 4; ni++)
                acc[mi][ni] = __builtin_amdgcn_mfma_f32_16x16x32_bf16(
                    aF[mi], bF[ni], acc[mi][ni], 0, 0, 0);
        __syncthreads();
    }

    // epilogue. D layout: col = lane&15 (n), row = (lane>>4)*4 + reg (m)   [m89]
    if (mode == 0) {
#pragma unroll
        for (int ni = 0; ni < 4; ni++) {
            int n = bn + wc * 64 + ni * 16 + l15;       // 0..3071
            int which = n >> 10;                         // 0=q 1=k 2=v
            int c = n & 1023;
            int nh = c >> 6, d = c & 63;
            const float* bias_p = (which == 0) ? bq : (which == 1) ? bk : bv;
            float bias = bias_p[c];
            float scl = (which == 0) ? 0.125f : 1.0f;
            bf16* dst = (which == 0) ? qh : (which == 1) ? kh : vh;
#pragma unroll
            for (int mi = 0; mi < 4; mi++) {
#pragma unroll
                for (int r = 0; r < 4; r++) {
                    int m = bm + wr * 64 + mi * 16 + g * 4 + r;  // token
                    int s = m >> 1, b = m & 1;
                    int head = b * NHEAD + nh;
                    dst[((size_t)(head * S_LEN + s)) * HDIM + d] =
                        (bf16)((acc[mi][ni][r] + bias) * scl);
                }
            }
        }
    } else {
#pragma unroll
        for (int ni = 0; ni < 4; ni++) {
            int n = bn + wc * 64 + ni * 16 + l15;
            float bias = bo[n];
#pragma unroll
            for (int mi = 0; mi < 4; mi++) {
#pragma unroll
                for (int r = 0; r < 4; r++) {
                    int m = bm + wr * 64 + mi * 16 + g * 4 + r;
                    outp[(size_t)m * HID + n] = acc[mi][ni][r] + bias;
                }
            }
        }
    }
}

// ---------------- V transpose: [32][2048][64] -> [32][64][2048] ----------------
__global__ void transpose_v(const bf16* __restrict__ v, bf16* __restrict__ vT) {
    __shared__ bf16 t[64][66];
    const int head = blockIdx.y;
    const int s0 = blockIdx.x * 64;
    const int tid = threadIdx.x;
#pragma unroll
    for (int i = 0; i < 2; i++) {
        int idx = (i * 256 + tid) * 8;
        int r = idx >> 6, c = idx & 63;
        bf16x8 vv = *(const bf16x8*)&v[((size_t)(head * S_LEN + s0 + r)) * HDIM + c];
#pragma unroll
        for (int j = 0; j < 8; j++) t[r][c + j] = vv[j];
    }
    __syncthreads();
#pragma unroll
    for (int i = 0; i < 2; i++) {
        int idx = (i * 256 + tid) * 8;
        int dr = idx >> 6, c = idx & 63;
        bf16x8 ov;
#pragma unroll
        for (int j = 0; j < 8; j++) ov[j] = t[c + j][dr];
        *(bf16x8*)&vT[((size_t)(head * HDIM + dr)) * S_LEN + s0 + c] = ov;
    }
}

// ---------------- flash attention ----------------
// grid: (64 st-tiles of 32, 16 nh). block 256 = 4 waves.
// wave wv: b = wv>>1, stsub = wv&1. Each wave: 16 q-rows, loop 32-key chunks.
__global__ __launch_bounds__(256) void attn(
    const bf16* __restrict__ q, const bf16* __restrict__ k, const bf16* __restrict__ vT,
    const float* __restrict__ amask,   // [16][2048][2048]
    const float* __restrict__ kmask,   // [32][2048]
    bf16* __restrict__ ctx)            // [4096][1024]
{
    __shared__ __align__(16) bf16 P[4][16][40];   // per-wave P tile, padded stride
    const int tid = threadIdx.x, lane = tid & 63, wv = tid >> 6;
    const int g = lane >> 4, l15 = lane & 15;
    const int b = wv >> 1, stsub = wv & 1;
    const int nh = blockIdx.y;
    const int st0 = blockIdx.x * 32 + stsub * 16;
    const int n = b * NHEAD + nh;

    const bf16* qrow = q + ((size_t)(n * S_LEN + st0 + l15)) * HDIM;
    bf16x8 aQ0 = *(const bf16x8*)(qrow + g * 8);
    bf16x8 aQ1 = *(const bf16x8*)(qrow + 32 + g * 8);

    f32x4 zero4 = {0.f, 0.f, 0.f, 0.f};
    f32x4 O[4];
#pragma unroll
    for (int t = 0; t < 4; t++) O[t] = zero4;
    float mrow[4] = {-INFINITY, -INFINITY, -INFINITY, -INFINITY};
    float lrow[4] = {0.f, 0.f, 0.f, 0.f};

    const float* amrow = amask + ((size_t)nh * S_LEN + st0) * S_LEN;
    const float* kmrow = kmask + (size_t)n * S_LEN;
    const bf16* vbase = vT + (size_t)n * HDIM * S_LEN;

    for (int tt0 = 0; tt0 < S_LEN; tt0 += 32) {
        // ---- QK^T: scores for 16 st x 32 tt ----
        const bf16* krow0 = k + ((size_t)(n * S_LEN + tt0 + l15)) * HDIM;
        const bf16* krow1 = krow0 + 16 * HDIM;
        bf16x8 bK00 = *(const bf16x8*)(krow0 + g * 8);
        bf16x8 bK01 = *(const bf16x8*)(krow0 + 32 + g * 8);
        bf16x8 bK10 = *(const bf16x8*)(krow1 + g * 8);
        bf16x8 bK11 = *(const bf16x8*)(krow1 + 32 + g * 8);
        f32x4 sc0 = zero4, sc1 = zero4;
        sc0 = __builtin_amdgcn_mfma_f32_16x16x32_bf16(aQ0, bK00, sc0, 0, 0, 0);
        sc0 = __builtin_amdgcn_mfma_f32_16x16x32_bf16(aQ1, bK01, sc0, 0, 0, 0);
        sc1 = __builtin_amdgcn_mfma_f32_16x16x32_bf16(aQ0, bK10, sc1, 0, 0, 0);
        sc1 = __builtin_amdgcn_mfma_f32_16x16x32_bf16(aQ1, bK11, sc1, 0, 0, 0);

        // ---- masks (fp32, the dominant HBM stream) ----
        float km0 = kmrow[tt0 + l15];
        float km1 = kmrow[tt0 + 16 + l15];
        float cmax[4];
#pragma unroll
        for (int r = 0; r < 4; r++) {
            const float* mp = amrow + (size_t)(g * 4 + r) * S_LEN + tt0 + l15;
            sc0[r] += mp[0] + km0;
            sc1[r] += mp[16] + km1;
            cmax[r] = fmaxf(sc0[r], sc1[r]);
        }
        // ---- online softmax: row-reduce across the 16-lane group ----
#pragma unroll
        for (int off = 1; off < 16; off <<= 1)
#pragma unroll
            for (int r = 0; r < 4; r++)
                cmax[r] = fmaxf(cmax[r], __shfl_xor(cmax[r], off, 64));
        float p0[4], p1[4], rs[4];
#pragma unroll
        for (int r = 0; r < 4; r++) {
            float mn = fmaxf(mrow[r], cmax[r]);
            float scale = __expf(mrow[r] - mn);
            mrow[r] = mn;
            p0[r] = __expf(sc0[r] - mn);
            p1[r] = __expf(sc1[r] - mn);
            rs[r] = p0[r] + p1[r];
            lrow[r] *= scale;
#pragma unroll
            for (int t = 0; t < 4; t++) O[t][r] *= scale;
        }
#pragma unroll
        for (int off = 1; off < 16; off <<= 1)
#pragma unroll
            for (int r = 0; r < 4; r++) rs[r] += __shfl_xor(rs[r], off, 64);
#pragma unroll
        for (int r = 0; r < 4; r++) lrow[r] += rs[r];

        // ---- P -> LDS (D layout) -> A-fragment layout ----
#pragma unroll
        for (int r = 0; r < 4; r++) {
            P[wv][g * 4 + r][l15] = (bf16)p0[r];
            P[wv][g * 4 + r][16 + l15] = (bf16)p1[r];
        }
        __syncthreads();
        bf16x8 aP = *(const bf16x8*)&P[wv][l15][g * 8];

        // ---- PV: O += P(16x32) @ V(32x64) ----
        const bf16* vrow = vbase + tt0 + g * 8;
#pragma unroll
        for (int dt = 0; dt < 4; dt++) {
            bf16x8 bV = *(const bf16x8*)(vrow + (size_t)(dt * 16 + l15) * S_LEN);
            O[dt] = __builtin_amdgcn_mfma_f32_16x16x32_bf16(aP, bV, O[dt], 0, 0, 0);
        }
        __syncthreads();
    }

    // ---- epilogue: ctx[token][h] bf16 ----
#pragma unroll
    for (int r = 0; r < 4; r++) {
        float inv = 1.0f / lrow[r];
        int s = st0 + g * 4 + r;
        int token = s * BATCH + b;
#pragma unroll
        for (int dt = 0; dt < 4; dt++) {
            int h = nh * HDIM + dt * 16 + l15;
            ctx[(size_t)token * HID + h] = (bf16)(O[dt][r] * inv);
        }
    }
}

extern "C" void kernel_launch(void* const* d_in, const int* in_sizes, int n_in,
                              void* d_out, int out_size, void* d_ws, size_t ws_size,
                              hipStream_t stream) {
    const float* hidden = (const float*)d_in[0];
    const float* amask  = (const float*)d_in[1];
    const float* kmask  = (const float*)d_in[2];
    const float* Wq = (const float*)d_in[3];
    const float* bq = (const float*)d_in[4];
    const float* Wk = (const float*)d_in[5];
    const float* bk = (const float*)d_in[6];
    const float* Wv = (const float*)d_in[7];
    const float* bv = (const float*)d_in[8];
    const float* Wo = (const float*)d_in[9];
    const float* bo = (const float*)d_in[10];
    float* out = (float*)d_out;

    char* ws = (char*)d_ws;
    bf16* Xb   = (bf16*)(ws);                       // 8 MB  [4096][1024]
    bf16* Wcat = (bf16*)(ws + (8u  << 20));         // 6 MB  [3072][1024]
    bf16* Wob  = (bf16*)(ws + (14u << 20));         // 2 MB  [1024][1024]
    bf16* qh   = (bf16*)(ws + (16u << 20));         // 8 MB  [32][2048][64]
    bf16* kh   = (bf16*)(ws + (24u << 20));         // 8 MB
    bf16* vh   = (bf16*)(ws + (32u << 20));         // 8 MB
    bf16* vT   = (bf16*)(ws + (40u << 20));         // 8 MB  [32][64][2048]
    bf16* ctx  = (bf16*)(ws + (48u << 20));         // 8 MB  [4096][1024]

    cvt_f32_bf16<<<2048, 256, 0, stream>>>(hidden, Xb, NTOK * HID);
    cvt_f32_bf16<<<512, 256, 0, stream>>>(Wq, Wcat,            HID * HID);
    cvt_f32_bf16<<<512, 256, 0, stream>>>(Wk, Wcat + HID * HID,  HID * HID);
    cvt_f32_bf16<<<512, 256, 0, stream>>>(Wv, Wcat + 2 * HID * HID, HID * HID);
    cvt_f32_bf16<<<512, 256, 0, stream>>>(Wo, Wob, HID * HID);

    gemm_bt<<<dim3(24, 32), 256, 0, stream>>>(Xb, Wcat, NTOK, 3 * HID, HID, 0,
                                              bq, bk, bv, bo, qh, kh, vh, nullptr);
    transpose_v<<<dim3(32, 32), 256, 0, stream>>>(vh, vT);
    attn<<<dim3(64, 16), 256, 0, stream>>>(qh, kh, vT, amask, kmask, ctx);
    gemm_bt<<<dim3(8, 32), 256, 0, stream>>>(ctx, Wob, NTOK, HID, HID, 1,
                                             bq, bk, bv, bo, qh, kh, vh, out);
}

// Round 2
// 372.838 us; speedup vs baseline: 1.0003x; 1.0003x over previous
//
#include <hip/hip_runtime.h>
#include <hip/hip_bf16.h>
#include <math.h>

#define S_LEN 2048
#define BATCH 2
#define HID 1024
#define NHEAD 16
#define HDIM 64
#define NTOK (S_LEN*BATCH)   // 4096

typedef __bf16 bf16;
typedef __bf16 bf16x8 __attribute__((ext_vector_type(8)));
typedef float f32x4 __attribute__((ext_vector_type(4)));

typedef const __attribute__((address_space(1))) unsigned int* gptr_t;
typedef __attribute__((address_space(3))) unsigned int* lptr_t;

__device__ __forceinline__ void gload16(const void* g, void* l) {
    __builtin_amdgcn_global_load_lds((gptr_t)g, (lptr_t)l, 16, 0, 0);
}

// ---------------- fp32 -> bf16 convert (8 elems/thread) ----------------
__global__ void cvt_f32_bf16(const float* __restrict__ src, bf16* __restrict__ dst, int n) {
    int i = (blockIdx.x * blockDim.x + threadIdx.x) * 8;
    if (i >= n) return;
    const float4* s = (const float4*)(src + i);
    float4 a = s[0], b = s[1];
    bf16x8 o;
    o[0] = (bf16)a.x; o[1] = (bf16)a.y; o[2] = (bf16)a.z; o[3] = (bf16)a.w;
    o[4] = (bf16)b.x; o[5] = (bf16)b.y; o[6] = (bf16)b.z; o[7] = (bf16)b.w;
    *(bf16x8*)(dst + i) = o;
}

// ---------------- GEMM: C[M][N] = A[M][K] * B[N][K]^T ----------------
// mode 0: QKV epilogue (N=3072): q/k -> head layout [32][2048][64]; v -> vT [32][64][2048]
// mode 1: OUT epilogue (N=1024): fp32 token-major + bias
#define BM 128
#define BN 128
#define BK 32

__global__ __launch_bounds__(256) void gemm_bt(
    const bf16* __restrict__ A, const bf16* __restrict__ B,
    int M, int N, int K, int mode,
    const float* __restrict__ bq, const float* __restrict__ bk,
    const float* __restrict__ bv, const float* __restrict__ bo,
    bf16* __restrict__ qh, bf16* __restrict__ kh, bf16* __restrict__ vT,
    float* __restrict__ outp)
{
    __shared__ __align__(16) bf16 As[BM * BK];
    __shared__ __align__(16) bf16 Bs[BN * BK];
    const int tid = threadIdx.x;
    const int lane = tid & 63, wv = tid >> 6;
    const int g = lane >> 4, l15 = lane & 15;
    const int wr = wv >> 1, wc = wv & 1;
    const int bm = blockIdx.y * BM, bn = blockIdx.x * BN;

    f32x4 zero4 = {0.f, 0.f, 0.f, 0.f};
    f32x4 acc[4][4];
#pragma unroll
    for (int mi = 0; mi < 4; mi++)
#pragma unroll
        for (int ni = 0; ni < 4; ni++) acc[mi][ni] = zero4;

    const int r0 = wv * 32 + (lane >> 2);
    const int c0 = (lane & 3) * 8;
    const bf16* Ag0 = A + (size_t)(bm + r0) * K + c0;
    const bf16* Ag1 = Ag0 + (size_t)16 * K;
    const bf16* Bg0 = B + (size_t)(bn + r0) * K + c0;
    const bf16* Bg1 = Bg0 + (size_t)16 * K;
    bf16* AsW = &As[(wv * 32) * BK];
    bf16* BsW = &Bs[(wv * 32) * BK];

    for (int k0 = 0; k0 < K; k0 += BK) {
        gload16(Ag0 + k0, AsW);
        gload16(Ag1 + k0, AsW + 16 * BK);
        gload16(Bg0 + k0, BsW);
        gload16(Bg1 + k0, BsW + 16 * BK);
        __syncthreads();

        bf16x8 aF[4], bF[4];
#pragma unroll
        for (int mi = 0; mi < 4; mi++)
            aF[mi] = *(const bf16x8*)&As[(wr * 64 + mi * 16 + l15) * BK + g * 8];
#pragma unroll
        for (int ni = 0; ni < 4; ni++)
            bF[ni] = *(const bf16x8*)&Bs[(wc * 64 + ni * 16 + l15) * BK + g * 8];
#pragma unroll
        for (int mi = 0; mi < 4; mi++)
#pragma unroll
            for (int ni = 0; ni < 4; ni++)
                acc[mi][ni] = __builtin_amdgcn_mfma_f32_16x16x32_bf16(
                    aF[mi], bF[ni], acc[mi][ni], 0, 0, 0);
        __syncthreads();
    }

    if (mode == 0) {
#pragma unroll
        for (int ni = 0; ni < 4; ni++) {
            int n = bn + wc * 64 + ni * 16 + l15;       // 0..3071
            int which = n >> 10;                         // 0=q 1=k 2=v
            int c = n & 1023;
            int nh = c >> 6, d = c & 63;
            const float* bias_p = (which == 0) ? bq : (which == 1) ? bk : bv;
            float bias = bias_p[c];
            float scl = (which == 0) ? 0.125f : 1.0f;
#pragma unroll
            for (int mi = 0; mi < 4; mi++) {
#pragma unroll
                for (int r = 0; r < 4; r++) {
                    int m = bm + wr * 64 + mi * 16 + g * 4 + r;  // token
                    int s = m >> 1, b = m & 1;
                    int head = b * NHEAD + nh;
                    bf16 val = (bf16)((acc[mi][ni][r] + bias) * scl);
                    if (which == 2)
                        vT[((size_t)(head * HDIM + d)) * S_LEN + s] = val;
                    else {
                        bf16* dst = (which == 0) ? qh : kh;
                        dst[((size_t)(head * S_LEN + s)) * HDIM + d] = val;
                    }
                }
            }
        }
    } else {
#pragma unroll
        for (int ni = 0; ni < 4; ni++) {
            int n = bn + wc * 64 + ni * 16 + l15;
            float bias = bo[n];
#pragma unroll
            for (int mi = 0; mi < 4; mi++) {
#pragma unroll
                for (int r = 0; r < 4; r++) {
                    int m = bm + wr * 64 + mi * 16 + g * 4 + r;
                    outp[(size_t)m * HID + n] = acc[mi][ni][r] + bias;
                }
            }
        }
    }
}

// ---------------- flash attention, barrier-free per-wave ----------------
// grid: (64 st-tiles of 32, 16 nh). block 256 = 4 waves (b = wv>>1, stsub = wv&1).
// Each wave: 16 q-rows, 64 keys/iter, mask register-prefetched 1 iter ahead.
__global__ __launch_bounds__(256, 4) void attn(
    const bf16* __restrict__ q, const bf16* __restrict__ k, const bf16* __restrict__ vT,
    const float* __restrict__ amask,   // [16][2048][2048]
    const float* __restrict__ kmask,   // [32][2048]
    bf16* __restrict__ ctx)            // [4096][1024]
{
    __shared__ __align__(16) bf16 P[4][16][72];   // stride 144B: conflict-free b128 reads
    const int tid = threadIdx.x, lane = tid & 63, wv = tid >> 6;
    const int g = lane >> 4, l15 = lane & 15;
    const int b = wv >> 1, stsub = wv & 1;
    const int nh = blockIdx.y;
    const int st0 = blockIdx.x * 32 + stsub * 16;
    const int n = b * NHEAD + nh;

    const bf16* qrow = q + ((size_t)(n * S_LEN + st0 + l15)) * HDIM;
    bf16x8 aQ0 = *(const bf16x8*)(qrow + g * 8);
    bf16x8 aQ1 = *(const bf16x8*)(qrow + 32 + g * 8);

    f32x4 zero4 = {0.f, 0.f, 0.f, 0.f};
    f32x4 O[4];
#pragma unroll
    for (int t = 0; t < 4; t++) O[t] = zero4;
    float mrow[4] = {-1e30f, -1e30f, -1e30f, -1e30f};
    float lrow[4] = {0.f, 0.f, 0.f, 0.f};

    // per-lane base pointers
    const float* amrow = amask + ((size_t)nh * S_LEN + st0 + g * 4) * S_LEN + l15;
    const float* kmrow = kmask + (size_t)n * S_LEN + l15;
    const bf16* kbase = k + ((size_t)n * S_LEN + l15) * HDIM + g * 8;
    const bf16* vbase = vT + ((size_t)n * HDIM + l15) * S_LEN + g * 8;

    // prefetch mask regs for iter 0
    float mk[4][4], km[4];
#pragma unroll
    for (int c = 0; c < 4; c++) {
        km[c] = kmrow[16 * c];
#pragma unroll
        for (int r = 0; r < 4; r++) mk[r][c] = amrow[(size_t)r * S_LEN + 16 * c];
    }

    for (int tt0 = 0; tt0 < S_LEN; tt0 += 64) {
        // ---- QK^T: 16 st x 64 tt (4 chunks of 16 keys) ----
        f32x4 sc[4];
#pragma unroll
        for (int c = 0; c < 4; c++) {
            const bf16* kp = kbase + (size_t)(tt0 + 16 * c) * HDIM;
            bf16x8 k0 = *(const bf16x8*)kp;
            bf16x8 k1 = *(const bf16x8*)(kp + 32);
            f32x4 s = zero4;
            s = __builtin_amdgcn_mfma_f32_16x16x32_bf16(aQ0, k0, s, 0, 0, 0);
            s = __builtin_amdgcn_mfma_f32_16x16x32_bf16(aQ1, k1, s, 0, 0, 0);
            sc[c] = s;
        }
        // ---- consume prefetched masks ----
#pragma unroll
        for (int c = 0; c < 4; c++)
#pragma unroll
            for (int r = 0; r < 4; r++)
                sc[c][r] += mk[r][c] + km[c];
        // ---- prefetch next iter's masks (HBM latency hides under softmax+PV) ----
        if (tt0 + 64 < S_LEN) {
            const float* am2 = amrow + tt0 + 64;
            const float* km2 = kmrow + tt0 + 64;
#pragma unroll
            for (int c = 0; c < 4; c++) {
                km[c] = km2[16 * c];
#pragma unroll
                for (int r = 0; r < 4; r++) mk[r][c] = am2[(size_t)r * S_LEN + 16 * c];
            }
        }
        // ---- online softmax ----
        float cm[4];
#pragma unroll
        for (int r = 0; r < 4; r++)
            cm[r] = fmaxf(fmaxf(sc[0][r], sc[1][r]), fmaxf(sc[2][r], sc[3][r]));
#pragma unroll
        for (int off = 1; off < 16; off <<= 1)
#pragma unroll
            for (int r = 0; r < 4; r++)
                cm[r] = fmaxf(cm[r], __shfl_xor(cm[r], off, 64));
        float grow = fmaxf(fmaxf(cm[0] - mrow[0], cm[1] - mrow[1]),
                           fmaxf(cm[2] - mrow[2], cm[3] - mrow[3]));
        if (!__all(grow <= 8.0f)) {   // defer-max: skip rescale when growth small
#pragma unroll
            for (int r = 0; r < 4; r++) {
                float mn = fmaxf(mrow[r], cm[r]);
                float sscale = __expf(mrow[r] - mn);
                mrow[r] = mn;
                lrow[r] *= sscale;
#pragma unroll
                for (int t = 0; t < 4; t++) O[t][r] *= sscale;
            }
        }
        float rs[4] = {0.f, 0.f, 0.f, 0.f};
        float p[4][4];
#pragma unroll
        for (int c = 0; c < 4; c++)
#pragma unroll
            for (int r = 0; r < 4; r++) {
                p[c][r] = __expf(sc[c][r] - mrow[r]);
                rs[r] += p[c][r];
            }
#pragma unroll
        for (int off = 1; off < 16; off <<= 1)
#pragma unroll
            for (int r = 0; r < 4; r++) rs[r] += __shfl_xor(rs[r], off, 64);
#pragma unroll
        for (int r = 0; r < 4; r++) lrow[r] += rs[r];

        // ---- P -> LDS (per-wave, no block barrier) ----
#pragma unroll
        for (int c = 0; c < 4; c++)
#pragma unroll
            for (int r = 0; r < 4; r++)
                P[wv][g * 4 + r][16 * c + l15] = (bf16)p[c][r];
        asm volatile("s_waitcnt lgkmcnt(0)" ::: "memory");
        __builtin_amdgcn_sched_barrier(0);
        bf16x8 aP0 = *(const bf16x8*)&P[wv][l15][g * 8];
        bf16x8 aP1 = *(const bf16x8*)&P[wv][l15][32 + g * 8];

        // ---- PV: O += P(16x64) @ V(64x64) ----
#pragma unroll
        for (int dt = 0; dt < 4; dt++) {
            const bf16* vp = vbase + (size_t)(dt * 16) * S_LEN + tt0;
            bf16x8 v0 = *(const bf16x8*)vp;
            bf16x8 v1 = *(const bf16x8*)(vp + 32);
            O[dt] = __builtin_amdgcn_mfma_f32_16x16x32_bf16(aP0, v0, O[dt], 0, 0, 0);
            O[dt] = __builtin_amdgcn_mfma_f32_16x16x32_bf16(aP1, v1, O[dt], 0, 0, 0);
        }
    }

    // ---- epilogue ----
#pragma unroll
    for (int r = 0; r < 4; r++) {
        float inv = 1.0f / lrow[r];
        int s = st0 + g * 4 + r;
        int token = s * BATCH + b;
#pragma unroll
        for (int dt = 0; dt < 4; dt++) {
            int h = nh * HDIM + dt * 16 + l15;
            ctx[(size_t)token * HID + h] = (bf16)(O[dt][r] * inv);
        }
    }
}

extern "C" void kernel_launch(void* const* d_in, const int* in_sizes, int n_in,
                              void* d_out, int out_size, void* d_ws, size_t ws_size,
                              hipStream_t stream) {
    const float* hidden = (const float*)d_in[0];
    const float* amask  = (const float*)d_in[1];
    const float* kmask  = (const float*)d_in[2];
    const float* Wq = (const float*)d_in[3];
    const float* bq = (const float*)d_in[4];
    const float* Wk = (const float*)d_in[5];
    const float* bk = (const float*)d_in[6];
    const float* Wv = (const float*)d_in[7];
    const float* bv = (const float*)d_in[8];
    const float* Wo = (const float*)d_in[9];
    const float* bo = (const float*)d_in[10];
    float* out = (float*)d_out;

    char* ws = (char*)d_ws;
    bf16* Xb   = (bf16*)(ws);                       // 8 MB  [4096][1024]
    bf16* Wcat = (bf16*)(ws + (8u  << 20));         // 6 MB  [3072][1024]
    bf16* Wob  = (bf16*)(ws + (14u << 20));         // 2 MB  [1024][1024]
    bf16* qh   = (bf16*)(ws + (16u << 20));         // 8 MB  [32][2048][64]
    bf16* kh   = (bf16*)(ws + (24u << 20));         // 8 MB
    bf16* vT   = (bf16*)(ws + (40u << 20));         // 8 MB  [32][64][2048]
    bf16* ctx  = (bf16*)(ws + (48u << 20));         // 8 MB  [4096][1024]

    cvt_f32_bf16<<<2048, 256, 0, stream>>>(hidden, Xb, NTOK * HID);
    cvt_f32_bf16<<<512, 256, 0, stream>>>(Wq, Wcat,              HID * HID);
    cvt_f32_bf16<<<512, 256, 0, stream>>>(Wk, Wcat + HID * HID,  HID * HID);
    cvt_f32_bf16<<<512, 256, 0, stream>>>(Wv, Wcat + 2 * HID * HID, HID * HID);
    cvt_f32_bf16<<<512, 256, 0, stream>>>(Wo, Wob, HID * HID);

    gemm_bt<<<dim3(24, 32), 256, 0, stream>>>(Xb, Wcat, NTOK, 3 * HID, HID, 0,
                                              bq, bk, bv, bo, qh, kh, vT, nullptr);
    attn<<<dim3(64, 16), 256, 0, stream>>>(qh, kh, vT, amask, kmask, ctx);
    gemm_bt<<<dim3(8, 32), 256, 0, stream>>>(ctx, Wob, NTOK, HID, HID, 1,
                                             bq, bk, bv, bo, qh, kh, vT, out);
}